// Round 13
// baseline (318.934 us; speedup 1.0000x reference)
//
#include <hip/hip_runtime.h>
#include <hip/hip_bf16.h>
#include <hip/hip_fp16.h>
#include <math.h>

#ifndef M_PI
#define M_PI 3.14159265358979323846
#endif

// Problem constants
#define NN 10000      // nodes
#define NE 160000     // edges
#define NC 16         // channels
#define NQ 5          // 2*order+1
#define NFR 10        // N_FREQ * N_RINGS
#define CQ 80         // NC*NQ
#define OP 80         // outputs per node
#define KTOT 800      // GEMM K
#define WSZ 64000     // 80*800 weight elements

#define MT 32         // edges per block (one wave, 2 m-tiles)
#define CSTRIDE 168   // chunk row stride in fp16 elems (160 + 8 pad)

typedef __attribute__((ext_vector_type(8))) _Float16 f16x8;
typedef __attribute__((ext_vector_type(4))) float f32x4;

// RNE float->fp16
static __device__ __forceinline__ unsigned short f2h_u(float f) {
    return __builtin_bit_cast(unsigned short, (_Float16)f);
}
static __device__ __forceinline__ unsigned pack2h(float lo, float hi) {
    return (unsigned)f2h_u(lo) | ((unsigned)f2h_u(hi) << 16);
}

// ---------------------------------------------------------------------------
// init: zero deg[] AND build fragment-ordered fp16 W tables (R10-verified map)
//   Wt_frag[((ks*5+nt)*64 + lane)*8 + j] = fp16(W at n=16*nt+lrow,
//                                               k = 32*ks + 8*quad + j)
// ---------------------------------------------------------------------------
__global__ void init_ws(const float* __restrict__ W1, const float* __restrict__ W2,
                        unsigned short* __restrict__ Wt1, unsigned short* __restrict__ Wt2,
                        int4* __restrict__ degz) {
    int i = blockIdx.x * blockDim.x + threadIdx.x;
    if (i < 2500) degz[i] = make_int4(0, 0, 0, 0);   // deg[10000] = 0
    if (i >= WSZ) return;
    int j    = i & 7;
    int lane = (i >> 3) & 63;
    int grp  = i >> 9;           // ks*5 + nt
    int ks   = grp / 5;
    int nt   = grp % 5;
    int quad = lane >> 4;
    int lrow = lane & 15;
    int n    = 16 * nt + lrow;
    int k    = 32 * ks + 8 * quad + j;   // natural k
    int fr = k / CQ, cq = k % CQ;
    int c = cq / NQ, q = cq % NQ;
    int f = fr / 2,  r = fr % 2;
    int o = n / NQ,  p = n % NQ;
    int src = ((((o * NC + c) * NQ + p) * NQ + q) * 5 + f) * 2 + r;
    Wt1[i] = f2h_u(W1[src]);
    Wt2[i] = f2h_u(W2[src]);
}

// ---------------------------------------------------------------------------
// CSR build (edge_index fixed for both layers; rebuilt each launch since the
// harness re-poisons d_ws). hist -> scan (one 256-thread block) -> fill.
// ---------------------------------------------------------------------------
__global__ void csr_hist(const int* __restrict__ ei, int* __restrict__ deg) {
    int e = blockIdx.x * blockDim.x + threadIdx.x;
    if (e < NE) atomicAdd(&deg[ei[2 * e + 1]], 1);
}

__global__ __launch_bounds__(256)
void csr_scan(const int* __restrict__ deg, int* __restrict__ off, int* __restrict__ cursor) {
    __shared__ int ps[256];
    const int tid = threadIdx.x;
    const int base = tid * 40;           // 256*40 = 10240 >= NN
    int s = 0;
    for (int i = 0; i < 40; ++i) { int idx = base + i; if (idx < NN) s += deg[idx]; }
    ps[tid] = s;
    __syncthreads();
    // Hillis-Steele inclusive scan
    for (int ofs = 1; ofs < 256; ofs <<= 1) {
        int v = (tid >= ofs) ? ps[tid - ofs] : 0;
        __syncthreads();
        ps[tid] += v;
        __syncthreads();
    }
    int run = (tid > 0) ? ps[tid - 1] : 0;   // exclusive prefix
    for (int i = 0; i < 40; ++i) {
        int idx = base + i;
        if (idx < NN) { off[idx] = run; cursor[idx] = run; run += deg[idx]; }
    }
}

__global__ void csr_fill(const int* __restrict__ ei, int* __restrict__ cursor,
                         int* __restrict__ eid) {
    int e = blockIdx.x * blockDim.x + threadIdx.x;
    if (e >= NE) return;
    int slot = atomicAdd(&cursor[ei[2 * e + 1]], 1);
    eid[slot] = e;
}

// ---------------------------------------------------------------------------
// Edge conv v12: R12's verified GEMM (single-wave block, 32 edges, dual
// m-tile B-sharing, 5x K-chunked A staging) with the atomic scatter replaced
// by PLAIN fp16 stores to msg[e][80]. R12 diagnosis: 12.8M per-lane fp32
// atomics = ~80 us L2-RMW floor, invariant to compute/occupancy — stores are
// line-coalesced and fire-and-forget.
// ---------------------------------------------------------------------------
__global__ __launch_bounds__(64)
void edge_conv_mfma(const float* __restrict__ xin, const int* __restrict__ ei,
                    const float* __restrict__ pre, const float* __restrict__ phi_arr,
                    const unsigned short* __restrict__ Wt, unsigned short* __restrict__ msg) {
    __shared__ __align__(16) unsigned short A_s[MT * CSTRIDE];  // 10,752 B

    const int tid = threadIdx.x;
    const int e0 = blockIdx.x * MT;     // NE = 5000 * 32 exactly

    // ---- per-edge prep: 2 threads/edge, half of cq each ----
    const int el   = tid >> 1;
    const int half = tid & 1;
    const int e    = e0 + el;
    const int src  = ei[2 * e];

    float s1, c1;
    sincosf(phi_arr[e], &s1, &c1);
    const float c2 = c1 * c1 - s1 * s1;
    const float s2 = 2.0f * c1 * s1;

    float xt[40];
    {
        const float4* xp = (const float4*)(xin + (size_t)src * CQ + 40 * half);
        #pragma unroll
        for (int k4 = 0; k4 < 10; ++k4) {
            float4 v = xp[k4];
            xt[4 * k4 + 0] = v.x; xt[4 * k4 + 1] = v.y;
            xt[4 * k4 + 2] = v.z; xt[4 * k4 + 3] = v.w;
        }
        #pragma unroll
        for (int cc = 0; cc < 8; ++cc) {
            float a1 = xt[cc * 5 + 1], b1 = xt[cc * 5 + 2];
            float a2 = xt[cc * 5 + 3], b2 = xt[cc * 5 + 4];
            xt[cc * 5 + 1] = c1 * a1 - s1 * b1;
            xt[cc * 5 + 2] = s1 * a1 + c1 * b1;
            xt[cc * 5 + 3] = c2 * a2 - s2 * b2;
            xt[cc * 5 + 4] = s2 * a2 + c2 * b2;
        }
    }
    float tv[NFR];
    #pragma unroll
    for (int fr = 0; fr < NFR; ++fr) tv[fr] = pre[(size_t)e * NFR + fr];

    const int lane = tid;
    const int lrow = lane & 15;
    const int quad = lane >> 4;

    f32x4 acc0[5], acc1[5];
    #pragma unroll
    for (int nt = 0; nt < 5; ++nt) {
        acc0[nt] = (f32x4){0.f, 0.f, 0.f, 0.f};
        acc1[nt] = (f32x4){0.f, 0.f, 0.f, 0.f};
    }

    const f16x8* __restrict__ wf = (const f16x8*)Wt;
    const unsigned short* As_row0 = &A_s[lrow * CSTRIDE];
    const unsigned short* As_row1 = &A_s[(16 + lrow) * CSTRIDE];

    #pragma unroll
    for (int ch = 0; ch < 5; ++ch) {
        #pragma unroll
        for (int frl = 0; frl < 2; ++frl) {
            const float tf = tv[2 * ch + frl];
            uint2* dp = (uint2*)&A_s[el * CSTRIDE + frl * CQ + 40 * half];
            #pragma unroll
            for (int j = 0; j < 10; ++j) {
                unsigned lo = pack2h(xt[4 * j + 0] * tf, xt[4 * j + 1] * tf);
                unsigned hi = pack2h(xt[4 * j + 2] * tf, xt[4 * j + 3] * tf);
                dp[j] = make_uint2(lo, hi);
            }
        }
        __syncthreads();

        #pragma unroll
        for (int s = 0; s < 5; ++s) {
            f16x8 a0 = *(const f16x8*)(As_row0 + 32 * s + 8 * quad);
            f16x8 a1 = *(const f16x8*)(As_row1 + 32 * s + 8 * quad);
            #pragma unroll
            for (int nt = 0; nt < 5; ++nt) {
                f16x8 b = wf[((5 * ch + s) * 5 + nt) * 64 + lane];
                acc0[nt] = __builtin_amdgcn_mfma_f32_16x16x32_f16(a0, b, acc0[nt], 0, 0, 0);
                acc1[nt] = __builtin_amdgcn_mfma_f32_16x16x32_f16(a1, b, acc1[nt], 0, 0, 0);
            }
        }
        __syncthreads();
    }

    // ---- plain fp16 stores: row = e0 + 4*quad + r (+16), col = 16*nt+lrow ----
    #pragma unroll
    for (int r = 0; r < 4; ++r) {
        const int er = 4 * quad + r;
        unsigned short* m0p = msg + (size_t)(e0 + er) * OP + lrow;
        unsigned short* m1p = msg + (size_t)(e0 + 16 + er) * OP + lrow;
        #pragma unroll
        for (int nt = 0; nt < 5; ++nt) {
            m0p[16 * nt] = f2h_u(acc0[nt][r]);
            m1p[16 * nt] = f2h_u(acc1[nt][r]);
        }
    }
}

// ---------------------------------------------------------------------------
// Fused epilogue with CSR gather: thread (n,c) sums msg[eid][5c..5c+5) over
// node n's edges (16 threads of a node read each 160B row together), adds
// selfint + bias (+ residual), applies the 7-sample nonlinearity.
// ---------------------------------------------------------------------------
__global__ void nonlin_fused(const unsigned short* __restrict__ msg,
                             const int* __restrict__ deg, const int* __restrict__ off,
                             const int* __restrict__ eid,
                             const float* __restrict__ xin, const float* __restrict__ Ws,
                             const float* __restrict__ b, const float* __restrict__ res,
                             float* __restrict__ out) {
    __shared__ float ws_s[NC * NC * NQ * NQ];  // 25.6 KB
    const int tid = threadIdx.x;
    for (int i = tid; i < NC * NC * NQ * NQ; i += blockDim.x) ws_s[i] = Ws[i];
    __syncthreads();

    int idx = blockIdx.x * blockDim.x + tid;   // over N*C = 160000
    if (idx >= NN * NC) return;
    int n = idx / NC, c = idx % NC;

    float a0 = b[c], a1v = 0.f, a2v = 0.f, a3 = 0.f, a4 = 0.f;

    // CSR gather of edge messages
    const int d  = deg[n];
    const int o0i = off[n];
    const _Float16* mh = (const _Float16*)msg;
    for (int jj = 0; jj < d; ++jj) {
        const int e = eid[o0i + jj];
        const _Float16* mp = mh + (size_t)e * OP + c * NQ;
        a0  += (float)mp[0];
        a1v += (float)mp[1];
        a2v += (float)mp[2];
        a3  += (float)mp[3];
        a4  += (float)mp[4];
    }

    // self-interaction (out ch o=c)
    {
        const float* xrow = xin + (size_t)n * CQ;
        const float* wsc = ws_s + c * 400;
        #pragma unroll
        for (int cp = 0; cp < NC; ++cp) {
            #pragma unroll
            for (int q = 0; q < NQ; ++q) {
                float xv = xrow[cp * NQ + q];
                const float* w = wsc + cp * 25 + q;
                a0  = fmaf(xv, w[0],  a0);
                a1v = fmaf(xv, w[5],  a1v);
                a2v = fmaf(xv, w[10], a2v);
                a3  = fmaf(xv, w[15], a3);
                a4  = fmaf(xv, w[20], a4);
            }
        }
    }
    if (res != nullptr) {
        const float* rp = res + (size_t)n * CQ + c * NQ;
        a0 += rp[0]; a1v += rp[1]; a2v += rp[2]; a3 += rp[3]; a4 += rp[4];
    }

    float o0 = 0.f, o1 = 0.f, o2 = 0.f, o3 = 0.f, o4 = 0.f;
    #pragma unroll
    for (int k = 0; k < 7; ++k) {
        float th = (float)(2.0 * M_PI / 7.0) * (float)k;
        float c1k = cosf(th), s1k = sinf(th);
        float c2k = cosf(2.0f * th), s2k = sinf(2.0f * th);
        float s = a0 + a1v * c1k + a2v * s1k + a3 * c2k + a4 * s2k;
        s = fmaxf(s, 0.0f);
        o0 += s;
        o1 += s * c1k; o2 += s * s1k;
        o3 += s * c2k; o4 += s * s2k;
    }
    const float i7 = 1.0f / 7.0f, t7 = 2.0f / 7.0f;
    float* op = out + (size_t)idx * NQ;
    op[0] = o0 * i7;
    op[1] = o1 * t7; op[2] = o2 * t7;
    op[3] = o3 * t7; op[4] = o4 * t7;
}

// ---------------------------------------------------------------------------
extern "C" void kernel_launch(void* const* d_in, const int* in_sizes, int n_in,
                              void* d_out, int out_size, void* d_ws, size_t ws_size,
                              hipStream_t stream) {
    const float* x    = (const float*)d_in[0];
    const int*   ei   = (const int*)d_in[1];
    const float* pre  = (const float*)d_in[2];
    const float* phi  = (const float*)d_in[3];
    const float* W1   = (const float*)d_in[4];
    const float* b1   = (const float*)d_in[5];
    const float* Ws1  = (const float*)d_in[6];
    const float* W2   = (const float*)d_in[7];
    const float* b2   = (const float*)d_in[8];
    const float* Ws2  = (const float*)d_in[9];
    float* out = (float*)d_out;

    // Workspace layout (all 16B-aligned):
    unsigned short* Wt1 = (unsigned short*)d_ws;            // 128 KB
    unsigned short* Wt2 = Wt1 + WSZ;                        // 128 KB
    unsigned short* msg = Wt2 + WSZ;                        // 25.6 MB (NE*80 fp16)
    float* h   = (float*)(msg + (size_t)NE * OP);           // 3.2 MB
    int* deg    = (int*)(h + (size_t)NN * OP);              // 40 KB
    int* off    = deg + NN;                                 // 40 KB
    int* cursor = off + NN;                                 // 40 KB
    int* eid    = cursor + NN;                              // 640 KB
    // total ~= 29.8 MB

    // init + CSR build (edge_index identical for both layers)
    init_ws<<<(WSZ + 255) / 256, 256, 0, stream>>>(W1, W2, Wt1, Wt2, (int4*)deg);
    csr_hist<<<(NE + 255) / 256, 256, 0, stream>>>(ei, deg);
    csr_scan<<<1, 256, 0, stream>>>(deg, off, cursor);
    csr_fill<<<(NE + 255) / 256, 256, 0, stream>>>(ei, cursor, eid);

    // Layer 1
    edge_conv_mfma<<<NE / MT, 64, 0, stream>>>(x, ei, pre, phi, Wt1, msg);
    nonlin_fused<<<(NN * NC + 255) / 256, 256, 0, stream>>>(msg, deg, off, eid,
                                                            x, Ws1, b1, nullptr, h);

    // Layer 2
    edge_conv_mfma<<<NE / MT, 64, 0, stream>>>(h, ei, pre, phi, Wt2, msg);
    nonlin_fused<<<(NN * NC + 255) / 256, 256, 0, stream>>>(msg, deg, off, eid,
                                                            h, Ws2, b2, x, out);
}

// Round 14
// 284.861 us; speedup vs baseline: 1.1196x; 1.1196x over previous
//
#include <hip/hip_runtime.h>
#include <hip/hip_bf16.h>
#include <hip/hip_fp16.h>
#include <math.h>

#ifndef M_PI
#define M_PI 3.14159265358979323846
#endif

// Problem constants
#define NN 10000      // nodes
#define NE 160000     // edges
#define NC 16         // channels
#define NQ 5          // 2*order+1
#define NFR 10        // N_FREQ * N_RINGS
#define CQ 80         // NC*NQ
#define OP 80         // outputs per node
#define KTOT 800      // GEMM K
#define WSZ 64000     // 80*800 weight elements

#define MT 32         // edges per block (one wave, 2 m-tiles)
#define CSTRIDE 168   // chunk row stride in fp16 elems (160 + 8 pad)

typedef __attribute__((ext_vector_type(8))) _Float16 f16x8;
typedef __attribute__((ext_vector_type(4))) float f32x4;

// RNE float->fp16
static __device__ __forceinline__ unsigned short f2h_u(float f) {
    return __builtin_bit_cast(unsigned short, (_Float16)f);
}
static __device__ __forceinline__ unsigned pack2h(float lo, float hi) {
    return (unsigned)f2h_u(lo) | ((unsigned)f2h_u(hi) << 16);
}

// ---------------------------------------------------------------------------
// init: zero deg[] AND build fragment-ordered fp16 W tables (R10-verified map)
// ---------------------------------------------------------------------------
__global__ void init_ws(const float* __restrict__ W1, const float* __restrict__ W2,
                        unsigned short* __restrict__ Wt1, unsigned short* __restrict__ Wt2,
                        int4* __restrict__ degz) {
    int i = blockIdx.x * blockDim.x + threadIdx.x;
    if (i < 2500) degz[i] = make_int4(0, 0, 0, 0);   // deg[10000] = 0
    if (i >= WSZ) return;
    int j    = i & 7;
    int lane = (i >> 3) & 63;
    int grp  = i >> 9;           // ks*5 + nt
    int ks   = grp / 5;
    int nt   = grp % 5;
    int quad = lane >> 4;
    int lrow = lane & 15;
    int n    = 16 * nt + lrow;
    int k    = 32 * ks + 8 * quad + j;   // natural k
    int fr = k / CQ, cq = k % CQ;
    int c = cq / NQ, q = cq % NQ;
    int f = fr / 2,  r = fr % 2;
    int o = n / NQ,  p = n % NQ;
    int src = ((((o * NC + c) * NQ + p) * NQ + q) * 5 + f) * 2 + r;
    Wt1[i] = f2h_u(W1[src]);
    Wt2[i] = f2h_u(W2[src]);
}

// ---------------------------------------------------------------------------
// CSR build. hist -> scan (one block) -> fill (slot[e] = CSR position of e).
// ---------------------------------------------------------------------------
__global__ void csr_hist(const int* __restrict__ ei, int* __restrict__ deg) {
    int e = blockIdx.x * blockDim.x + threadIdx.x;
    if (e < NE) atomicAdd(&deg[ei[2 * e + 1]], 1);
}

__global__ __launch_bounds__(256)
void csr_scan(const int* __restrict__ deg, int* __restrict__ off, int* __restrict__ cursor) {
    __shared__ int ps[256];
    const int tid = threadIdx.x;
    const int base = tid * 40;           // 256*40 = 10240 >= NN
    int s = 0;
    for (int i = 0; i < 40; ++i) { int idx = base + i; if (idx < NN) s += deg[idx]; }
    ps[tid] = s;
    __syncthreads();
    for (int ofs = 1; ofs < 256; ofs <<= 1) {
        int v = (tid >= ofs) ? ps[tid - ofs] : 0;
        __syncthreads();
        ps[tid] += v;
        __syncthreads();
    }
    int run = (tid > 0) ? ps[tid - 1] : 0;   // exclusive prefix
    for (int i = 0; i < 40; ++i) {
        int idx = base + i;
        if (idx < NN) { off[idx] = run; cursor[idx] = run; run += deg[idx]; }
    }
}

__global__ void csr_fill(const int* __restrict__ ei, int* __restrict__ cursor,
                         int* __restrict__ slot) {
    int e = blockIdx.x * blockDim.x + threadIdx.x;
    if (e >= NE) return;
    slot[e] = atomicAdd(&cursor[ei[2 * e + 1]], 1);
}

// ---------------------------------------------------------------------------
// Edge conv v13: R13's verified GEMM; msg rows written at CSR position
// slot[e] instead of e, so the gather reads sequential rows (no eid
// indirection). Plain fp16 stores (atomic-free — R13's confirmed win).
// ---------------------------------------------------------------------------
__global__ __launch_bounds__(64)
void edge_conv_mfma(const float* __restrict__ xin, const int* __restrict__ ei,
                    const float* __restrict__ pre, const float* __restrict__ phi_arr,
                    const unsigned short* __restrict__ Wt, const int* __restrict__ slot,
                    unsigned short* __restrict__ msg) {
    __shared__ __align__(16) unsigned short A_s[MT * CSTRIDE];  // 10,752 B

    const int tid = threadIdx.x;
    const int e0 = blockIdx.x * MT;     // NE = 5000 * 32 exactly

    const int el   = tid >> 1;
    const int half = tid & 1;
    const int e    = e0 + el;
    const int src  = ei[2 * e];

    float s1, c1;
    sincosf(phi_arr[e], &s1, &c1);
    const float c2 = c1 * c1 - s1 * s1;
    const float s2 = 2.0f * c1 * s1;

    float xt[40];
    {
        const float4* xp = (const float4*)(xin + (size_t)src * CQ + 40 * half);
        #pragma unroll
        for (int k4 = 0; k4 < 10; ++k4) {
            float4 v = xp[k4];
            xt[4 * k4 + 0] = v.x; xt[4 * k4 + 1] = v.y;
            xt[4 * k4 + 2] = v.z; xt[4 * k4 + 3] = v.w;
        }
        #pragma unroll
        for (int cc = 0; cc < 8; ++cc) {
            float a1 = xt[cc * 5 + 1], b1 = xt[cc * 5 + 2];
            float a2 = xt[cc * 5 + 3], b2 = xt[cc * 5 + 4];
            xt[cc * 5 + 1] = c1 * a1 - s1 * b1;
            xt[cc * 5 + 2] = s1 * a1 + c1 * b1;
            xt[cc * 5 + 3] = c2 * a2 - s2 * b2;
            xt[cc * 5 + 4] = s2 * a2 + c2 * b2;
        }
    }
    float tv[NFR];
    #pragma unroll
    for (int fr = 0; fr < NFR; ++fr) tv[fr] = pre[(size_t)e * NFR + fr];

    const int lane = tid;
    const int lrow = lane & 15;
    const int quad = lane >> 4;

    f32x4 acc0[5], acc1[5];
    #pragma unroll
    for (int nt = 0; nt < 5; ++nt) {
        acc0[nt] = (f32x4){0.f, 0.f, 0.f, 0.f};
        acc1[nt] = (f32x4){0.f, 0.f, 0.f, 0.f};
    }

    const f16x8* __restrict__ wf = (const f16x8*)Wt;
    const unsigned short* As_row0 = &A_s[lrow * CSTRIDE];
    const unsigned short* As_row1 = &A_s[(16 + lrow) * CSTRIDE];

    #pragma unroll
    for (int ch = 0; ch < 5; ++ch) {
        #pragma unroll
        for (int frl = 0; frl < 2; ++frl) {
            const float tf = tv[2 * ch + frl];
            uint2* dp = (uint2*)&A_s[el * CSTRIDE + frl * CQ + 40 * half];
            #pragma unroll
            for (int j = 0; j < 10; ++j) {
                unsigned lo = pack2h(xt[4 * j + 0] * tf, xt[4 * j + 1] * tf);
                unsigned hi = pack2h(xt[4 * j + 2] * tf, xt[4 * j + 3] * tf);
                dp[j] = make_uint2(lo, hi);
            }
        }
        __syncthreads();

        #pragma unroll
        for (int s = 0; s < 5; ++s) {
            f16x8 a0 = *(const f16x8*)(As_row0 + 32 * s + 8 * quad);
            f16x8 a1 = *(const f16x8*)(As_row1 + 32 * s + 8 * quad);
            #pragma unroll
            for (int nt = 0; nt < 5; ++nt) {
                f16x8 b = wf[((5 * ch + s) * 5 + nt) * 64 + lane];
                acc0[nt] = __builtin_amdgcn_mfma_f32_16x16x32_f16(a0, b, acc0[nt], 0, 0, 0);
                acc1[nt] = __builtin_amdgcn_mfma_f32_16x16x32_f16(a1, b, acc1[nt], 0, 0, 0);
            }
        }
        __syncthreads();
    }

    // ---- fp16 stores at CSR row slot[e]: col = 16*nt + lrow ----
    #pragma unroll
    for (int r = 0; r < 4; ++r) {
        const int er = 4 * quad + r;
        const int s0 = slot[e0 + er];
        const int s1r = slot[e0 + 16 + er];
        unsigned short* m0p = msg + (size_t)s0 * OP + lrow;
        unsigned short* m1p = msg + (size_t)s1r * OP + lrow;
        #pragma unroll
        for (int nt = 0; nt < 5; ++nt) {
            m0p[16 * nt] = f2h_u(acc0[nt][r]);
            m1p[16 * nt] = f2h_u(acc1[nt][r]);
        }
    }
}

// ---------------------------------------------------------------------------
// Fused epilogue: CSR gather over SEQUENTIAL msg rows + selfint (transposed
// Ws in LDS: ws_t[(cp*25+p*5+q)*16 + c] — 16 consecutive banks across c,
// same-address broadcast across the 4 node-groups of a wave; R13's layout
// (c*400+...) put all 64 lanes on 2 banks = 32-way conflict, 1.16e7 cycles).
// ---------------------------------------------------------------------------
__global__ void nonlin_fused(const unsigned short* __restrict__ msg,
                             const int* __restrict__ deg, const int* __restrict__ off,
                             const float* __restrict__ xin, const float* __restrict__ Ws,
                             const float* __restrict__ b, const float* __restrict__ res,
                             float* __restrict__ out) {
    __shared__ float ws_t[NC * NC * NQ * NQ];  // 25.6 KB, transposed layout
    const int tid = threadIdx.x;
    for (int i = tid; i < NC * NC * NQ * NQ; i += blockDim.x) {
        int c   = i & 15;          // lane-minor
        int rst = i >> 4;          // cp*25 + p*5 + q
        int cp = rst / 25, pq = rst % 25;
        int p = pq / 5, q = pq % 5;
        ws_t[i] = Ws[c * 400 + cp * 25 + p * 5 + q];
    }
    __syncthreads();

    int idx = blockIdx.x * blockDim.x + tid;   // over N*C = 160000
    if (idx >= NN * NC) return;
    int n = idx / NC, c = idx % NC;

    float a0 = b[c], a1v = 0.f, a2v = 0.f, a3 = 0.f, a4 = 0.f;

    // CSR gather: rows off[n]..off[n]+deg[n]-1 are contiguous in msg
    const int d   = deg[n];
    const int ro  = off[n];
    const _Float16* mh = (const _Float16*)msg + (size_t)ro * OP + c * NQ;
    for (int jj = 0; jj < d; ++jj) {
        const _Float16* mp = mh + (size_t)jj * OP;
        a0  += (float)mp[0];
        a1v += (float)mp[1];
        a2v += (float)mp[2];
        a3  += (float)mp[3];
        a4  += (float)mp[4];
    }

    // self-interaction (out ch o=c), conflict-free transposed LDS
    {
        const float* xrow = xin + (size_t)n * CQ;
        #pragma unroll
        for (int cp = 0; cp < NC; ++cp) {
            #pragma unroll
            for (int q = 0; q < NQ; ++q) {
                float xv = xrow[cp * NQ + q];
                const float* w = ws_t + (cp * 25 + q) * 16 + c;
                a0  = fmaf(xv, w[0 * 80],  a0);    // p=0: (cp*25+0*5+q)*16+c
                a1v = fmaf(xv, w[1 * 80],  a1v);   // p=1
                a2v = fmaf(xv, w[2 * 80],  a2v);
                a3  = fmaf(xv, w[3 * 80],  a3);
                a4  = fmaf(xv, w[4 * 80],  a4);
            }
        }
    }
    if (res != nullptr) {
        const float* rp = res + (size_t)n * CQ + c * NQ;
        a0 += rp[0]; a1v += rp[1]; a2v += rp[2]; a3 += rp[3]; a4 += rp[4];
    }

    float o0 = 0.f, o1 = 0.f, o2 = 0.f, o3 = 0.f, o4 = 0.f;
    #pragma unroll
    for (int k = 0; k < 7; ++k) {
        float th = (float)(2.0 * M_PI / 7.0) * (float)k;
        float c1k = cosf(th), s1k = sinf(th);
        float c2k = cosf(2.0f * th), s2k = sinf(2.0f * th);
        float s = a0 + a1v * c1k + a2v * s1k + a3 * c2k + a4 * s2k;
        s = fmaxf(s, 0.0f);
        o0 += s;
        o1 += s * c1k; o2 += s * s1k;
        o3 += s * c2k; o4 += s * s2k;
    }
    const float i7 = 1.0f / 7.0f, t7 = 2.0f / 7.0f;
    float* op = out + (size_t)idx * NQ;
    op[0] = o0 * i7;
    op[1] = o1 * t7; op[2] = o2 * t7;
    op[3] = o3 * t7; op[4] = o4 * t7;
}

// ---------------------------------------------------------------------------
extern "C" void kernel_launch(void* const* d_in, const int* in_sizes, int n_in,
                              void* d_out, int out_size, void* d_ws, size_t ws_size,
                              hipStream_t stream) {
    const float* x    = (const float*)d_in[0];
    const int*   ei   = (const int*)d_in[1];
    const float* pre  = (const float*)d_in[2];
    const float* phi  = (const float*)d_in[3];
    const float* W1   = (const float*)d_in[4];
    const float* b1   = (const float*)d_in[5];
    const float* Ws1  = (const float*)d_in[6];
    const float* W2   = (const float*)d_in[7];
    const float* b2   = (const float*)d_in[8];
    const float* Ws2  = (const float*)d_in[9];
    float* out = (float*)d_out;

    // Workspace layout (16B-aligned)
    unsigned short* Wt1 = (unsigned short*)d_ws;            // 128 KB
    unsigned short* Wt2 = Wt1 + WSZ;                        // 128 KB
    unsigned short* msg = Wt2 + WSZ;                        // 25.6 MB
    float* h   = (float*)(msg + (size_t)NE * OP);           // 3.2 MB
    int* deg    = (int*)(h + (size_t)NN * OP);              // 40 KB
    int* off    = deg + NN;                                 // 40 KB
    int* cursor = off + NN;                                 // 40 KB
    int* slot   = cursor + NN;                              // 640 KB

    init_ws<<<(WSZ + 255) / 256, 256, 0, stream>>>(W1, W2, Wt1, Wt2, (int4*)deg);
    csr_hist<<<(NE + 255) / 256, 256, 0, stream>>>(ei, deg);
    csr_scan<<<1, 256, 0, stream>>>(deg, off, cursor);
    csr_fill<<<(NE + 255) / 256, 256, 0, stream>>>(ei, cursor, slot);

    // Layer 1
    edge_conv_mfma<<<NE / MT, 64, 0, stream>>>(x, ei, pre, phi, Wt1, slot, msg);
    nonlin_fused<<<(NN * NC + 255) / 256, 256, 0, stream>>>(msg, deg, off,
                                                            x, Ws1, b1, nullptr, h);

    // Layer 2
    edge_conv_mfma<<<NE / MT, 64, 0, stream>>>(h, ei, pre, phi, Wt2, slot, msg);
    nonlin_fused<<<(NN * NC + 255) / 256, 256, 0, stream>>>(msg, deg, off,
                                                            h, Ws2, b2, x, out);
}